// Round 1
// baseline (1885.052 us; speedup 1.0000x reference)
//
#include <hip/hip_runtime.h>

#define B_   2
#define NSU  2076
#define NSV  8940
#define ROWS_SU (B_ * NSU)            // 4152
#define ROWS_ALL (B_ * (NSU + NSV))   // 22032
#define NB2_SU 17                     // ceil(2076/128)
#define NB2_SV 70                     // ceil(8940/128)
#define NEG_INF (-3.402823466e38f)

// ---------------- pre: y1 = x @ W_c1 ; init = x @ W_fc1 + b_fc1 ----------------
__global__ __launch_bounds__(256) void pre_kernel(
    const float* __restrict__ x_su, const float* __restrict__ x_sv,
    const float* __restrict__ Wc1, const float* __restrict__ Wfc1,
    const float* __restrict__ bfc1,
    float* __restrict__ y1_su, float* __restrict__ y1_sv,
    float* __restrict__ init_su, float* __restrict__ init_sv)
{
    __shared__ float sWc1[64 * 64];
    __shared__ float sWfc1[64 * 32];
    __shared__ float sb[32];
    const int tid = threadIdx.x;
    for (int i = tid; i < 64 * 64; i += 256) sWc1[i] = Wc1[i];
    for (int i = tid; i < 64 * 32; i += 256) sWfc1[i] = Wfc1[i];
    if (tid < 32) sb[tid] = bfc1[tid];
    __syncthreads();

    const int rid = blockIdx.x * 256 + tid;
    if (rid >= ROWS_ALL) return;

    const float* xrow;
    float* y1out;
    float* initout;
    if (rid < ROWS_SU) {
        xrow = x_su + (size_t)rid * 64;
        y1out = y1_su + (size_t)rid * 64;
        initout = init_su + (size_t)rid * 32;
    } else {
        const int r = rid - ROWS_SU;
        xrow = x_sv + (size_t)r * 64;
        y1out = y1_sv + (size_t)r * 64;
        initout = init_sv + (size_t)r * 32;
    }

    float xr[64];
    #pragma unroll
    for (int f4 = 0; f4 < 16; ++f4) {
        float4 v = ((const float4*)xrow)[f4];
        xr[f4 * 4 + 0] = v.x; xr[f4 * 4 + 1] = v.y;
        xr[f4 * 4 + 2] = v.z; xr[f4 * 4 + 3] = v.w;
    }
    for (int c = 0; c < 64; ++c) {
        float acc = 0.f;
        #pragma unroll
        for (int f = 0; f < 64; ++f) acc += xr[f] * sWc1[f * 64 + c];
        y1out[c] = acc;
    }
    for (int c = 0; c < 32; ++c) {
        float acc = sb[c];
        #pragma unroll
        for (int f = 0; f < 64; ++f) acc += xr[f] * sWfc1[f * 32 + c];
        initout[c] = acc;
    }
}

// ---------------- conv1: h = relu(adj @ y1 + b_c1) ----------------
// tile: 64 rows x 64 cols, K-chunk 32, 256 threads (16x16), 4x4 per thread
__global__ __launch_bounds__(256) void conv1_kernel(
    const float* __restrict__ adj_su, const float* __restrict__ adj_sv,
    const float* __restrict__ y1_su, const float* __restrict__ y1_sv,
    const float* __restrict__ bc1,
    float* __restrict__ h_su, float* __restrict__ h_sv)
{
    const int by = blockIdx.y;
    int M; const float* A; const float* Bm; float* H;
    if (by < 2) {
        M = NSU;
        A  = adj_su + (size_t)by * NSU * NSU;
        Bm = y1_su + (size_t)by * NSU * 64;
        H  = h_su  + (size_t)by * NSU * 64;
    } else {
        const int b = by - 2;
        M = NSV;
        A  = adj_sv + (size_t)b * NSV * NSV;
        Bm = y1_sv + (size_t)b * NSV * 64;
        H  = h_sv  + (size_t)b * NSV * 64;
    }
    const int row0 = blockIdx.x * 64;
    if (row0 >= M) return;

    __shared__ float As[32][68];   // transposed: As[k][row], padded
    __shared__ float Bs[32][64];

    const int tid = threadIdx.x;
    const int tx = tid & 15;
    const int ty = tid >> 4;

    float acc[4][4] = {};

    for (int kk = 0; kk < M; kk += 32) {
        #pragma unroll
        for (int l = 0; l < 2; ++l) {
            const int idx = tid + l * 256;        // 0..511
            const int r = idx >> 3;               // 0..63
            const int kq = idx & 7;
            const int grow = row0 + r;
            const int gcol = kk + kq * 4;
            float4 v = make_float4(0.f, 0.f, 0.f, 0.f);
            if (grow < M) {
                if (gcol + 3 < M) {
                    v = *(const float4*)(A + (size_t)grow * M + gcol);
                } else {
                    v.x = (gcol + 0 < M) ? A[(size_t)grow * M + gcol + 0] : 0.f;
                    v.y = (gcol + 1 < M) ? A[(size_t)grow * M + gcol + 1] : 0.f;
                    v.z = (gcol + 2 < M) ? A[(size_t)grow * M + gcol + 2] : 0.f;
                    v.w = (gcol + 3 < M) ? A[(size_t)grow * M + gcol + 3] : 0.f;
                }
            }
            As[kq * 4 + 0][r] = v.x;
            As[kq * 4 + 1][r] = v.y;
            As[kq * 4 + 2][r] = v.z;
            As[kq * 4 + 3][r] = v.w;
        }
        #pragma unroll
        for (int l = 0; l < 2; ++l) {
            const int idx = tid + l * 256;
            const int k = idx >> 4;               // 0..31
            const int q = idx & 15;
            const int gk = kk + k;
            float4 v = make_float4(0.f, 0.f, 0.f, 0.f);
            if (gk < M) v = *(const float4*)(Bm + (size_t)gk * 64 + q * 4);
            *(float4*)&Bs[k][q * 4] = v;
        }
        __syncthreads();
        #pragma unroll
        for (int k = 0; k < 32; ++k) {
            float a0 = As[k][ty * 4 + 0], a1 = As[k][ty * 4 + 1];
            float a2 = As[k][ty * 4 + 2], a3 = As[k][ty * 4 + 3];
            float b0 = Bs[k][tx * 4 + 0], b1 = Bs[k][tx * 4 + 1];
            float b2 = Bs[k][tx * 4 + 2], b3 = Bs[k][tx * 4 + 3];
            acc[0][0] += a0 * b0; acc[0][1] += a0 * b1; acc[0][2] += a0 * b2; acc[0][3] += a0 * b3;
            acc[1][0] += a1 * b0; acc[1][1] += a1 * b1; acc[1][2] += a1 * b2; acc[1][3] += a1 * b3;
            acc[2][0] += a2 * b0; acc[2][1] += a2 * b1; acc[2][2] += a2 * b2; acc[2][3] += a2 * b3;
            acc[3][0] += a3 * b0; acc[3][1] += a3 * b1; acc[3][2] += a3 * b2; acc[3][3] += a3 * b3;
        }
        __syncthreads();
    }

    float bb0 = bc1[tx * 4 + 0], bb1 = bc1[tx * 4 + 1];
    float bb2 = bc1[tx * 4 + 2], bb3 = bc1[tx * 4 + 3];
    #pragma unroll
    for (int i = 0; i < 4; ++i) {
        const int r = row0 + ty * 4 + i;
        if (r < M) {
            float4 v;
            v.x = fmaxf(acc[i][0] + bb0, 0.f);
            v.y = fmaxf(acc[i][1] + bb1, 0.f);
            v.z = fmaxf(acc[i][2] + bb2, 0.f);
            v.w = fmaxf(acc[i][3] + bb3, 0.f);
            *(float4*)(H + (size_t)r * 64 + tx * 4) = v;
        }
    }
}

// ---------------- mid: y2 = h @ W_c2 ----------------
__global__ __launch_bounds__(256) void mid_kernel(
    const float* __restrict__ h_su, const float* __restrict__ h_sv,
    const float* __restrict__ Wc2,
    float* __restrict__ y2_su, float* __restrict__ y2_sv)
{
    __shared__ float sW[64 * 32];
    const int tid = threadIdx.x;
    for (int i = tid; i < 64 * 32; i += 256) sW[i] = Wc2[i];
    __syncthreads();

    const int rid = blockIdx.x * 256 + tid;
    if (rid >= ROWS_ALL) return;

    const float* hrow;
    float* yout;
    if (rid < ROWS_SU) {
        hrow = h_su + (size_t)rid * 64;
        yout = y2_su + (size_t)rid * 32;
    } else {
        const int r = rid - ROWS_SU;
        hrow = h_sv + (size_t)r * 64;
        yout = y2_sv + (size_t)r * 32;
    }
    float hr[64];
    #pragma unroll
    for (int f4 = 0; f4 < 16; ++f4) {
        float4 v = ((const float4*)hrow)[f4];
        hr[f4 * 4 + 0] = v.x; hr[f4 * 4 + 1] = v.y;
        hr[f4 * 4 + 2] = v.z; hr[f4 * 4 + 3] = v.w;
    }
    for (int c = 0; c < 32; ++c) {
        float acc = 0.f;
        #pragma unroll
        for (int f = 0; f < 64; ++f) acc += hr[f] * sW[f * 32 + c];
        yout[c] = acc;
    }
}

// ---------------- conv2: partials of max_n(adj @ y2 + b_c2 + init) ----------------
// tile: 128 rows x 32 cols, K-chunk 32, 256 threads (8x32), 4x4 per thread
__global__ __launch_bounds__(256) void conv2_kernel(
    const float* __restrict__ adj_su, const float* __restrict__ adj_sv,
    const float* __restrict__ y2_su, const float* __restrict__ y2_sv,
    const float* __restrict__ init_su, const float* __restrict__ init_sv,
    const float* __restrict__ bc2,
    float* __restrict__ part_su, float* __restrict__ part_sv)
{
    const int by = blockIdx.y;
    int M; const float* A; const float* Bm; const float* I; float* P;
    if (by < 2) {
        M = NSU;
        A  = adj_su + (size_t)by * NSU * NSU;
        Bm = y2_su + (size_t)by * NSU * 32;
        I  = init_su + (size_t)by * NSU * 32;
        P  = part_su + (size_t)by * NB2_SU * 32;
    } else {
        const int b = by - 2;
        M = NSV;
        A  = adj_sv + (size_t)b * NSV * NSV;
        Bm = y2_sv + (size_t)b * NSV * 32;
        I  = init_sv + (size_t)b * NSV * 32;
        P  = part_sv + (size_t)b * NB2_SV * 32;
    }
    const int row0 = blockIdx.x * 128;
    if (row0 >= M) return;

    __shared__ float As[32][132];
    __shared__ float Bs[32][32];
    __shared__ float red[32][33];

    const int tid = threadIdx.x;
    const int tx = tid & 7;     // col quad: cols tx*4..tx*4+3
    const int ty = tid >> 3;    // 0..31: rows ty*4..ty*4+3

    float acc[4][4] = {};

    for (int kk = 0; kk < M; kk += 32) {
        #pragma unroll
        for (int l = 0; l < 4; ++l) {
            const int idx = tid + l * 256;        // 0..1023
            const int r = idx >> 3;               // 0..127
            const int kq = idx & 7;
            const int grow = row0 + r;
            const int gcol = kk + kq * 4;
            float4 v = make_float4(0.f, 0.f, 0.f, 0.f);
            if (grow < M) {
                if (gcol + 3 < M) {
                    v = *(const float4*)(A + (size_t)grow * M + gcol);
                } else {
                    v.x = (gcol + 0 < M) ? A[(size_t)grow * M + gcol + 0] : 0.f;
                    v.y = (gcol + 1 < M) ? A[(size_t)grow * M + gcol + 1] : 0.f;
                    v.z = (gcol + 2 < M) ? A[(size_t)grow * M + gcol + 2] : 0.f;
                    v.w = (gcol + 3 < M) ? A[(size_t)grow * M + gcol + 3] : 0.f;
                }
            }
            As[kq * 4 + 0][r] = v.x;
            As[kq * 4 + 1][r] = v.y;
            As[kq * 4 + 2][r] = v.z;
            As[kq * 4 + 3][r] = v.w;
        }
        {
            const int k = tid >> 3;               // 0..31
            const int q = tid & 7;                // 0..7
            const int gk = kk + k;
            float4 v = make_float4(0.f, 0.f, 0.f, 0.f);
            if (gk < M) v = *(const float4*)(Bm + (size_t)gk * 32 + q * 4);
            *(float4*)&Bs[k][q * 4] = v;
        }
        __syncthreads();
        #pragma unroll
        for (int k = 0; k < 32; ++k) {
            float a0 = As[k][ty * 4 + 0], a1 = As[k][ty * 4 + 1];
            float a2 = As[k][ty * 4 + 2], a3 = As[k][ty * 4 + 3];
            float b0 = Bs[k][tx * 4 + 0], b1 = Bs[k][tx * 4 + 1];
            float b2 = Bs[k][tx * 4 + 2], b3 = Bs[k][tx * 4 + 3];
            acc[0][0] += a0 * b0; acc[0][1] += a0 * b1; acc[0][2] += a0 * b2; acc[0][3] += a0 * b3;
            acc[1][0] += a1 * b0; acc[1][1] += a1 * b1; acc[1][2] += a1 * b2; acc[1][3] += a1 * b3;
            acc[2][0] += a2 * b0; acc[2][1] += a2 * b1; acc[2][2] += a2 * b2; acc[2][3] += a2 * b3;
            acc[3][0] += a3 * b0; acc[3][1] += a3 * b1; acc[3][2] += a3 * b2; acc[3][3] += a3 * b3;
        }
        __syncthreads();
    }

    float bb0 = bc2[tx * 4 + 0], bb1 = bc2[tx * 4 + 1];
    float bb2 = bc2[tx * 4 + 2], bb3 = bc2[tx * 4 + 3];
    float cm0 = NEG_INF, cm1 = NEG_INF, cm2 = NEG_INF, cm3 = NEG_INF;
    #pragma unroll
    for (int i = 0; i < 4; ++i) {
        const int r = row0 + ty * 4 + i;
        if (r < M) {
            float4 iv = *(const float4*)(I + (size_t)r * 32 + tx * 4);
            cm0 = fmaxf(cm0, acc[i][0] + bb0 + iv.x);
            cm1 = fmaxf(cm1, acc[i][1] + bb1 + iv.y);
            cm2 = fmaxf(cm2, acc[i][2] + bb2 + iv.z);
            cm3 = fmaxf(cm3, acc[i][3] + bb3 + iv.w);
        }
    }
    red[ty][tx * 4 + 0] = cm0;
    red[ty][tx * 4 + 1] = cm1;
    red[ty][tx * 4 + 2] = cm2;
    red[ty][tx * 4 + 3] = cm3;
    __syncthreads();
    if (tid < 32) {
        float m = NEG_INF;
        #pragma unroll
        for (int t = 0; t < 32; ++t) m = fmaxf(m, red[t][tid]);
        P[(size_t)blockIdx.x * 32 + tid] = m;
    }
}

// ---------------- head: pool-reduce + 4-layer MLP ----------------
__global__ __launch_bounds__(128) void head_kernel(
    const float* __restrict__ part_su, const float* __restrict__ part_sv,
    const float* __restrict__ Wfc2, const float* __restrict__ bfc2,
    const float* __restrict__ Wfc3, const float* __restrict__ bfc3,
    const float* __restrict__ Wfc4, const float* __restrict__ bfc4,
    const float* __restrict__ Wfc5, const float* __restrict__ bfc5,
    float* __restrict__ out)
{
    __shared__ float d[2][64];
    __shared__ float t1[2][32];
    __shared__ float t2[2][64];
    __shared__ float t3[2][32];
    const int tid = threadIdx.x;

    if (tid < 64) {
        const int b = tid >> 5, c = tid & 31;
        float m = NEG_INF;
        for (int i = 0; i < NB2_SU; ++i) m = fmaxf(m, part_su[(size_t)(b * NB2_SU + i) * 32 + c]);
        d[b][c] = m;
        float m2 = NEG_INF;
        for (int i = 0; i < NB2_SV; ++i) m2 = fmaxf(m2, part_sv[(size_t)(b * NB2_SV + i) * 32 + c]);
        d[b][32 + c] = m2;
    }
    __syncthreads();
    if (tid < 64) {
        const int b = tid >> 5, c = tid & 31;
        float acc = bfc2[c];
        for (int f = 0; f < 64; ++f) acc += d[b][f] * Wfc2[f * 32 + c];
        t1[b][c] = fmaxf(acc, 0.f);
    }
    __syncthreads();
    {
        const int b = tid >> 6, c = tid & 63;
        float acc = bfc3[c];
        for (int f = 0; f < 32; ++f) acc += t1[b][f] * Wfc3[f * 64 + c];
        t2[b][c] = fmaxf(acc, 0.f);
    }
    __syncthreads();
    if (tid < 64) {
        const int b = tid >> 5, c = tid & 31;
        float acc = bfc4[c];
        for (int f = 0; f < 64; ++f) acc += t2[b][f] * Wfc4[f * 32 + c];
        t3[b][c] = fmaxf(acc, 0.f);
    }
    __syncthreads();
    if (tid < 2) {
        float acc = bfc5[0];
        for (int f = 0; f < 32; ++f) acc += t3[tid][f] * Wfc5[f];
        out[tid] = acc;
    }
}

extern "C" void kernel_launch(void* const* d_in, const int* in_sizes, int n_in,
                              void* d_out, int out_size, void* d_ws, size_t ws_size,
                              hipStream_t stream)
{
    const float* solute_adj   = (const float*)d_in[0];
    const float* solute_meth  = (const float*)d_in[1];
    const float* solvent_meth = (const float*)d_in[2];
    const float* solvent_adj  = (const float*)d_in[3];
    const float* W_fc1 = (const float*)d_in[4];
    const float* b_fc1 = (const float*)d_in[5];
    const float* W_c1  = (const float*)d_in[6];
    const float* b_c1  = (const float*)d_in[7];
    const float* W_c2  = (const float*)d_in[8];
    const float* b_c2  = (const float*)d_in[9];
    const float* W_fc2 = (const float*)d_in[10];
    const float* b_fc2 = (const float*)d_in[11];
    const float* W_fc3 = (const float*)d_in[12];
    const float* b_fc3 = (const float*)d_in[13];
    const float* W_fc4 = (const float*)d_in[14];
    const float* b_fc4 = (const float*)d_in[15];
    const float* W_fc5 = (const float*)d_in[16];
    const float* b_fc5 = (const float*)d_in[17];
    float* out = (float*)d_out;

    float* ws = (float*)d_ws;
    size_t off = 0;
    float* y1_su = ws + off;   off += (size_t)B_ * NSU * 64;
    float* y1_sv = ws + off;   off += (size_t)B_ * NSV * 64;
    float* h_su = ws + off;    off += (size_t)B_ * NSU * 64;
    float* h_sv = ws + off;    off += (size_t)B_ * NSV * 64;
    float* init_su = ws + off; off += (size_t)B_ * NSU * 32;
    float* init_sv = ws + off; off += (size_t)B_ * NSV * 32;
    float* y2_su = ws + off;   off += (size_t)B_ * NSU * 32;
    float* y2_sv = ws + off;   off += (size_t)B_ * NSV * 32;
    float* part_su = ws + off; off += (size_t)B_ * NB2_SU * 32;
    float* part_sv = ws + off; off += (size_t)B_ * NB2_SV * 32;

    pre_kernel<<<dim3((ROWS_ALL + 255) / 256), dim3(256), 0, stream>>>(
        solute_meth, solvent_meth, W_c1, W_fc1, b_fc1, y1_su, y1_sv, init_su, init_sv);

    conv1_kernel<<<dim3((NSV + 63) / 64, 4), dim3(256), 0, stream>>>(
        solute_adj, solvent_adj, y1_su, y1_sv, b_c1, h_su, h_sv);

    mid_kernel<<<dim3((ROWS_ALL + 255) / 256), dim3(256), 0, stream>>>(
        h_su, h_sv, W_c2, y2_su, y2_sv);

    conv2_kernel<<<dim3((NSV + 127) / 128, 4), dim3(256), 0, stream>>>(
        solute_adj, solvent_adj, y2_su, y2_sv, init_su, init_sv, b_c2, part_su, part_sv);

    head_kernel<<<dim3(1), dim3(128), 0, stream>>>(
        part_su, part_sv, W_fc2, b_fc2, W_fc3, b_fc3, W_fc4, b_fc4, W_fc5, b_fc5, out);
}

// Round 2
// 786.022 us; speedup vs baseline: 2.3982x; 2.3982x over previous
//
#include <hip/hip_runtime.h>

#define B_      2
#define NSU     2076
#define NSV     8940
#define ROWS_SU (B_ * NSU)            // 4152
#define ROWS_ALL (B_ * (NSU + NSV))   // 22032
#define NBLK_SU 130                   // ceil(2076/16)
#define NBLK_SV 559                   // ceil(8940/16)
#define MP_SU   2176                  // ceil(2076/128)*128
#define MP_SV   8960                  // ceil(8940/128)*128
#define NEG_INF (-3.402823466e38f)

typedef __attribute__((ext_vector_type(8))) short bf16x8;
typedef __attribute__((ext_vector_type(4))) float f32x4;

__device__ __forceinline__ unsigned short f2bf(float x) {
    // round-to-nearest-even fp32 -> bf16 (finite inputs)
    unsigned int u = __float_as_uint(x);
    u += 0x7FFFu + ((u >> 16) & 1u);
    return (unsigned short)(u >> 16);
}

// ---------------- pre: y1t = (x @ W_c1)^T bf16 ; init = x @ W_fc1 + b_fc1 ----------------
__global__ __launch_bounds__(256) void pre_kernel(
    const float* __restrict__ xsu, const float* __restrict__ xsv,
    const float* __restrict__ Wc1, const float* __restrict__ Wfc1,
    const float* __restrict__ bfc1,
    unsigned short* __restrict__ y1t, float* __restrict__ initb)
{
    __shared__ float sWc1[64 * 64];
    __shared__ float sWfc1[64 * 32];
    __shared__ float sb[32];
    const int tid = threadIdx.x;
    for (int i = tid; i < 64 * 64; i += 256) sWc1[i] = Wc1[i];
    for (int i = tid; i < 64 * 32; i += 256) sWfc1[i] = Wfc1[i];
    if (tid < 32) sb[tid] = bfc1[tid];
    __syncthreads();

    const int rid = blockIdx.x * 256 + tid;
    if (rid >= ROWS_ALL) return;

    const float* xrow; unsigned short* yt; int m; size_t MPl;
    if (rid < ROWS_SU) {
        int b = rid / NSU; m = rid - b * NSU;
        xrow = xsu + (size_t)rid * 64;
        yt = y1t + (size_t)b * 64 * MP_SU; MPl = MP_SU;
    } else {
        int r2 = rid - ROWS_SU;
        int b = r2 / NSV; m = r2 - b * NSV;
        xrow = xsv + (size_t)r2 * 64;
        yt = y1t + (size_t)2 * 64 * MP_SU + (size_t)b * 64 * MP_SV; MPl = MP_SV;
    }

    float xr[64];
    #pragma unroll
    for (int f4 = 0; f4 < 16; ++f4) {
        float4 v = ((const float4*)xrow)[f4];
        xr[f4 * 4 + 0] = v.x; xr[f4 * 4 + 1] = v.y;
        xr[f4 * 4 + 2] = v.z; xr[f4 * 4 + 3] = v.w;
    }
    for (int c = 0; c < 64; ++c) {
        float acc = 0.f;
        #pragma unroll
        for (int f = 0; f < 64; ++f) acc += xr[f] * sWc1[f * 64 + c];
        yt[(size_t)c * MPl + m] = f2bf(acc);
    }
    float* ini = initb + (size_t)rid * 32;
    for (int c = 0; c < 32; ++c) {
        float acc = sb[c];
        #pragma unroll
        for (int f = 0; f < 64; ++f) acc += xr[f] * sWfc1[f * 32 + c];
        ini[c] = acc;
    }
}

// ---------------- conv1 (+fused mid): y2t = ((relu(adj@y1 + b_c1)) @ W_c2)^T bf16 --------
// 1 block = 16 output rows x 64 cols; 4 waves = 4 col-groups; barrier-free MFMA K-loop.
__global__ __launch_bounds__(256) void conv1_kernel(
    const float* __restrict__ adj_su, const float* __restrict__ adj_sv,
    const unsigned short* __restrict__ y1t,
    const float* __restrict__ bc1, const float* __restrict__ Wc2g,
    unsigned short* __restrict__ y2t)
{
    const int tid = threadIdx.x;
    __shared__ float sWc2[64][32];
    __shared__ float sh[16][68];
    for (int i = tid; i < 2048; i += 256) sWc2[i >> 5][i & 31] = Wc2g[i];

    const int bid = blockIdx.x;
    int M, MP, row0;
    const float* A; const unsigned short* Yt; unsigned short* Y2;
    if (bid < 2 * NBLK_SV) {                       // solvent first (long blocks)
        int b = bid / NBLK_SV, rb = bid - b * NBLK_SV;
        M = NSV; MP = MP_SV;
        A  = adj_sv + (size_t)b * NSV * NSV;
        Yt = y1t + (size_t)2 * 64 * MP_SU + (size_t)b * 64 * MP_SV;
        Y2 = y2t + (size_t)2 * 32 * MP_SU + (size_t)b * 32 * MP_SV;
        row0 = rb * 16;
    } else {
        int t = bid - 2 * NBLK_SV;
        int b = t / NBLK_SU, rb = t - b * NBLK_SU;
        M = NSU; MP = MP_SU;
        A  = adj_su + (size_t)b * NSU * NSU;
        Yt = y1t + (size_t)b * 64 * MP_SU;
        Y2 = y2t + (size_t)b * 32 * MP_SU;
        row0 = rb * 16;
    }

    const int lane = tid & 63;
    const int wid  = tid >> 6;       // col-group: cols wid*16..wid*16+15
    const int l15  = lane & 15;
    const int kq   = lane >> 4;      // 0..3
    const int gr   = row0 + l15;
    const int grc  = (gr < M) ? gr : (M - 1);
    const float* Ap  = A + (size_t)grc * M;
    const float* Apk = Ap + kq * 8;
    const unsigned short* Bp = Yt + (size_t)(wid * 16 + l15) * MP + kq * 8;
    const float bc = bc1[wid * 16 + l15];

    f32x4 acc = {0.f, 0.f, 0.f, 0.f};
    const int NF = (M / 64) * 64;
    for (int k0 = 0; k0 < NF; k0 += 64) {
        float4 a0 = *(const float4*)(Apk + k0);
        float4 a1 = *(const float4*)(Apk + k0 + 4);
        float4 a2 = *(const float4*)(Apk + k0 + 32);
        float4 a3 = *(const float4*)(Apk + k0 + 36);
        bf16x8 f0, f1;
        f0[0] = f2bf(a0.x); f0[1] = f2bf(a0.y); f0[2] = f2bf(a0.z); f0[3] = f2bf(a0.w);
        f0[4] = f2bf(a1.x); f0[5] = f2bf(a1.y); f0[6] = f2bf(a1.z); f0[7] = f2bf(a1.w);
        f1[0] = f2bf(a2.x); f1[1] = f2bf(a2.y); f1[2] = f2bf(a2.z); f1[3] = f2bf(a2.w);
        f1[4] = f2bf(a3.x); f1[5] = f2bf(a3.y); f1[6] = f2bf(a3.z); f1[7] = f2bf(a3.w);
        bf16x8 b0 = *(const bf16x8*)(Bp + k0);
        bf16x8 b1 = *(const bf16x8*)(Bp + k0 + 32);
        acc = __builtin_amdgcn_mfma_f32_16x16x32_bf16(f0, b0, acc, 0, 0, 0);
        acc = __builtin_amdgcn_mfma_f32_16x16x32_bf16(f1, b1, acc, 0, 0, 0);
    }
    if (NF < M) {
        const int k0 = NF;
        bf16x8 f0, f1;
        #pragma unroll
        for (int e = 0; e < 8; ++e) {
            int ka = k0 + kq * 8 + e;
            int kb = ka + 32;
            f0[e] = (ka < M) ? (short)f2bf(Ap[ka]) : (short)0;
            f1[e] = (kb < M) ? (short)f2bf(Ap[kb]) : (short)0;
        }
        bf16x8 b0 = *(const bf16x8*)(Bp + k0);
        bf16x8 b1 = *(const bf16x8*)(Bp + k0 + 32);
        acc = __builtin_amdgcn_mfma_f32_16x16x32_bf16(f0, b0, acc, 0, 0, 0);
        acc = __builtin_amdgcn_mfma_f32_16x16x32_bf16(f1, b1, acc, 0, 0, 0);
    }

    // h tile -> LDS (C/D layout: col=lane&15, row=kq*4+j)
    #pragma unroll
    for (int j = 0; j < 4; ++j)
        sh[kq * 4 + j][wid * 16 + l15] = fmaxf(acc[j] + bc, 0.f);
    __syncthreads();

    // fused mid: y2[r][c] = sum_f h[r][f] * Wc2[f][c]; write transposed bf16
    const int c  = tid >> 3;       // 0..31
    const int rg = tid & 7;        // rows rg*2, rg*2+1
    float s0 = 0.f, s1 = 0.f;
    #pragma unroll
    for (int f = 0; f < 64; ++f) {
        float w = sWc2[f][c];
        s0 += sh[rg * 2][f] * w;
        s1 += sh[rg * 2 + 1][f] * w;
    }
    unsigned int pk = (unsigned int)f2bf(s0) | ((unsigned int)f2bf(s1) << 16);
    *(unsigned int*)(Y2 + (size_t)c * MP + row0 + rg * 2) = pk;
}

// ---------------- conv2: part[blk][c] = max_r (adj@y2 + b_c2 + init) -------------------
// 1 block = 16 rows x 32 cols; 4 waves = 2 col-groups x 2 k-groups; in-block split-K.
__global__ __launch_bounds__(256) void conv2_kernel(
    const float* __restrict__ adj_su, const float* __restrict__ adj_sv,
    const unsigned short* __restrict__ y2t,
    const float* __restrict__ bc2, const float* __restrict__ initb,
    float* __restrict__ part)
{
    const int bid = blockIdx.x;
    int M, MP, row0;
    const float* A; const unsigned short* Yt; const float* I; float* P;
    if (bid < 2 * NBLK_SV) {
        int b = bid / NBLK_SV, rb = bid - b * NBLK_SV;
        M = NSV; MP = MP_SV;
        A  = adj_sv + (size_t)b * NSV * NSV;
        Yt = y2t + (size_t)2 * 32 * MP_SU + (size_t)b * 32 * MP_SV;
        I  = initb + (size_t)ROWS_SU * 32 + (size_t)b * NSV * 32;
        P  = part + (size_t)(2 * NBLK_SU + b * NBLK_SV + rb) * 32;
        row0 = rb * 16;
    } else {
        int t = bid - 2 * NBLK_SV;
        int b = t / NBLK_SU, rb = t - b * NBLK_SU;
        M = NSU; MP = MP_SU;
        A  = adj_su + (size_t)b * NSU * NSU;
        Yt = y2t + (size_t)b * 32 * MP_SU;
        I  = initb + (size_t)b * NSU * 32;
        P  = part + (size_t)(b * NBLK_SU + rb) * 32;
        row0 = rb * 16;
    }

    const int tid = threadIdx.x;
    const int lane = tid & 63;
    const int wid  = tid >> 6;
    const int cg = wid & 1, kg = wid >> 1;
    const int l15 = lane & 15, kq = lane >> 4;
    const int gr  = row0 + l15;
    const int grc = (gr < M) ? gr : (M - 1);
    const float* Ap  = A + (size_t)grc * M;
    const float* Apk = Ap + kg * 64 + kq * 8;
    const unsigned short* Bp = Yt + (size_t)(cg * 16 + l15) * MP + kg * 64 + kq * 8;

    f32x4 acc = {0.f, 0.f, 0.f, 0.f};
    const int NF = (M / 128) * 128;
    for (int k0 = 0; k0 < NF; k0 += 128) {
        float4 a0 = *(const float4*)(Apk + k0);
        float4 a1 = *(const float4*)(Apk + k0 + 4);
        float4 a2 = *(const float4*)(Apk + k0 + 32);
        float4 a3 = *(const float4*)(Apk + k0 + 36);
        bf16x8 f0, f1;
        f0[0] = f2bf(a0.x); f0[1] = f2bf(a0.y); f0[2] = f2bf(a0.z); f0[3] = f2bf(a0.w);
        f0[4] = f2bf(a1.x); f0[5] = f2bf(a1.y); f0[6] = f2bf(a1.z); f0[7] = f2bf(a1.w);
        f1[0] = f2bf(a2.x); f1[1] = f2bf(a2.y); f1[2] = f2bf(a2.z); f1[3] = f2bf(a2.w);
        f1[4] = f2bf(a3.x); f1[5] = f2bf(a3.y); f1[6] = f2bf(a3.z); f1[7] = f2bf(a3.w);
        bf16x8 b0 = *(const bf16x8*)(Bp + k0);
        bf16x8 b1 = *(const bf16x8*)(Bp + k0 + 32);
        acc = __builtin_amdgcn_mfma_f32_16x16x32_bf16(f0, b0, acc, 0, 0, 0);
        acc = __builtin_amdgcn_mfma_f32_16x16x32_bf16(f1, b1, acc, 0, 0, 0);
    }
    if (NF < M) {
        const int base = NF + kg * 64 + kq * 8;
        bf16x8 f0, f1;
        #pragma unroll
        for (int e = 0; e < 8; ++e) {
            int ka = base + e;
            int kb = base + 32 + e;
            f0[e] = (ka < M) ? (short)f2bf(Ap[ka]) : (short)0;
            f1[e] = (kb < M) ? (short)f2bf(Ap[kb]) : (short)0;
        }
        bf16x8 b0 = *(const bf16x8*)(Bp + NF);
        bf16x8 b1 = *(const bf16x8*)(Bp + NF + 32);
        acc = __builtin_amdgcn_mfma_f32_16x16x32_bf16(f0, b0, acc, 0, 0, 0);
        acc = __builtin_amdgcn_mfma_f32_16x16x32_bf16(f1, b1, acc, 0, 0, 0);
    }

    __shared__ float red[2][16][33];
    #pragma unroll
    for (int j = 0; j < 4; ++j)
        red[kg][kq * 4 + j][cg * 16 + l15] = acc[j];
    __syncthreads();

    const int r = tid >> 4, c0 = tid & 15;
    const int grr = row0 + r;
    const bool ok = grr < M;
    float v0 = NEG_INF, v1 = NEG_INF;
    if (ok) {
        float i0 = I[(size_t)grr * 32 + c0];
        float i1 = I[(size_t)grr * 32 + c0 + 16];
        v0 = red[0][r][c0]      + red[1][r][c0]      + bc2[c0]      + i0;
        v1 = red[0][r][c0 + 16] + red[1][r][c0 + 16] + bc2[c0 + 16] + i1;
    }
    __syncthreads();
    red[0][r][c0] = v0; red[0][r][c0 + 16] = v1;
    __syncthreads();
    if (tid < 32) {
        float m = NEG_INF;
        #pragma unroll
        for (int rr = 0; rr < 16; ++rr) m = fmaxf(m, red[0][rr][tid]);
        P[tid] = m;
    }
}

// ---------------- head: pool-reduce + 4-layer MLP ----------------
__global__ __launch_bounds__(128) void head_kernel(
    const float* __restrict__ part,
    const float* __restrict__ Wfc2, const float* __restrict__ bfc2,
    const float* __restrict__ Wfc3, const float* __restrict__ bfc3,
    const float* __restrict__ Wfc4, const float* __restrict__ bfc4,
    const float* __restrict__ Wfc5, const float* __restrict__ bfc5,
    float* __restrict__ out)
{
    __shared__ float d[2][64];
    __shared__ float t1[2][32];
    __shared__ float t2[2][64];
    __shared__ float t3[2][32];
    const int tid = threadIdx.x;

    if (tid < 64) {
        const int b = tid >> 5, c = tid & 31;
        float m = NEG_INF;
        const float* ps = part + (size_t)b * NBLK_SU * 32 + c;
        for (int i = 0; i < NBLK_SU; ++i) m = fmaxf(m, ps[(size_t)i * 32]);
        d[b][c] = m;
        float m2 = NEG_INF;
        const float* pv = part + (size_t)(2 * NBLK_SU + b * NBLK_SV) * 32 + c;
        for (int i = 0; i < NBLK_SV; ++i) m2 = fmaxf(m2, pv[(size_t)i * 32]);
        d[b][32 + c] = m2;
    }
    __syncthreads();
    if (tid < 64) {
        const int b = tid >> 5, c = tid & 31;
        float acc = bfc2[c];
        for (int f = 0; f < 64; ++f) acc += d[b][f] * Wfc2[f * 32 + c];
        t1[b][c] = fmaxf(acc, 0.f);
    }
    __syncthreads();
    {
        const int b = tid >> 6, c = tid & 63;
        float acc = bfc3[c];
        for (int f = 0; f < 32; ++f) acc += t1[b][f] * Wfc3[f * 64 + c];
        t2[b][c] = fmaxf(acc, 0.f);
    }
    __syncthreads();
    if (tid < 64) {
        const int b = tid >> 5, c = tid & 31;
        float acc = bfc4[c];
        for (int f = 0; f < 64; ++f) acc += t2[b][f] * Wfc4[f * 32 + c];
        t3[b][c] = fmaxf(acc, 0.f);
    }
    __syncthreads();
    if (tid < 2) {
        float acc = bfc5[0];
        for (int f = 0; f < 32; ++f) acc += t3[tid][f] * Wfc5[f];
        out[tid] = acc;
    }
}

extern "C" void kernel_launch(void* const* d_in, const int* in_sizes, int n_in,
                              void* d_out, int out_size, void* d_ws, size_t ws_size,
                              hipStream_t stream)
{
    const float* solute_adj   = (const float*)d_in[0];
    const float* solute_meth  = (const float*)d_in[1];
    const float* solvent_meth = (const float*)d_in[2];
    const float* solvent_adj  = (const float*)d_in[3];
    const float* W_fc1 = (const float*)d_in[4];
    const float* b_fc1 = (const float*)d_in[5];
    const float* W_c1  = (const float*)d_in[6];
    const float* b_c1  = (const float*)d_in[7];
    const float* W_c2  = (const float*)d_in[8];
    const float* b_c2  = (const float*)d_in[9];
    const float* W_fc2 = (const float*)d_in[10];
    const float* b_fc2 = (const float*)d_in[11];
    const float* W_fc3 = (const float*)d_in[12];
    const float* b_fc3 = (const float*)d_in[13];
    const float* W_fc4 = (const float*)d_in[14];
    const float* b_fc4 = (const float*)d_in[15];
    const float* W_fc5 = (const float*)d_in[16];
    const float* b_fc5 = (const float*)d_in[17];
    float* out = (float*)d_out;

    // workspace layout (bytes)
    char* wsb = (char*)d_ws;
    unsigned short* y1t = (unsigned short*)(wsb);                       // 1425408 elems
    unsigned short* y2t = (unsigned short*)(wsb + 2850816);             //  712704 elems
    float* initb        = (float*)(wsb + 2850816 + 1425408);            //  705024 f32
    float* part         = (float*)(wsb + 2850816 + 1425408 + 2820096);  //   44096 f32

    pre_kernel<<<dim3((ROWS_ALL + 255) / 256), dim3(256), 0, stream>>>(
        solute_meth, solvent_meth, W_c1, W_fc1, b_fc1, y1t, initb);

    const int NB = 2 * NBLK_SV + 2 * NBLK_SU;   // 1378
    conv1_kernel<<<dim3(NB), dim3(256), 0, stream>>>(
        solute_adj, solvent_adj, y1t, b_c1, W_c2, y2t);

    conv2_kernel<<<dim3(NB), dim3(256), 0, stream>>>(
        solute_adj, solvent_adj, y2t, b_c2, initb, part);

    head_kernel<<<dim3(1), dim3(128), 0, stream>>>(
        part, W_fc2, b_fc2, W_fc3, b_fc3, W_fc4, b_fc4, W_fc5, b_fc5, out);
}

// Round 3
// 635.744 us; speedup vs baseline: 2.9651x; 1.2364x over previous
//
#include <hip/hip_runtime.h>

#define B_      2
#define NSU     2076
#define NSV     8940
#define ROWS_SU (B_ * NSU)            // 4152
#define ROWS_ALL (B_ * (NSU + NSV))   // 22032
#define MP_SU   2176
#define MP_SV   8960
#define NB64_SV 140                   // 8960/64
#define NB64_SU 33                    // 2112/64
#define KH_SV   4480                  // K-split point (mult of 64)
#define KH_SU   1024
#define T_SV    560                   // 16-row tiles per solvent batch
#define T_SU    132
#define TILES_TOT (2 * T_SV + 2 * T_SU)   // 1384
#define PADROWS (TILES_TOT * 16)          // 22144
#define NEG_INF (-3.402823466e38f)

typedef __attribute__((ext_vector_type(8))) short bf16x8;
typedef __attribute__((ext_vector_type(4))) float f32x4;

union BF8 { bf16x8 v; unsigned int u[4]; };

#define MFMA16 __builtin_amdgcn_mfma_f32_16x16x32_bf16

__device__ __forceinline__ unsigned short f2bf(float x) {
    unsigned int u = __float_as_uint(x);
    u += 0x7FFFu + ((u >> 16) & 1u);
    return (unsigned short)(u >> 16);
}
__device__ __forceinline__ unsigned int pkbf(float lo, float hi) {
    unsigned int r;
    asm("v_cvt_pk_bf16_f32 %0, %1, %2" : "=v"(r) : "v"(lo), "v"(hi));
    return r;
}

// ---------------- pre: y1t = (x @ W_c1)^T bf16 ; init = x @ W_fc1 + b_fc1 ----------------
__global__ __launch_bounds__(256) void pre_kernel(
    const float* __restrict__ xsu, const float* __restrict__ xsv,
    const float* __restrict__ Wc1, const float* __restrict__ Wfc1,
    const float* __restrict__ bfc1,
    unsigned short* __restrict__ y1t, float* __restrict__ initb)
{
    __shared__ float sWc1[64 * 64];
    __shared__ float sWfc1[64 * 32];
    __shared__ float sb[32];
    const int tid = threadIdx.x;
    for (int i = tid; i < 64 * 64; i += 256) sWc1[i] = Wc1[i];
    for (int i = tid; i < 64 * 32; i += 256) sWfc1[i] = Wfc1[i];
    if (tid < 32) sb[tid] = bfc1[tid];
    __syncthreads();

    const int rid = blockIdx.x * 256 + tid;
    if (rid >= ROWS_ALL) return;

    const float* xrow; unsigned short* yt; int m; size_t MPl;
    if (rid < ROWS_SU) {
        int b = rid / NSU; m = rid - b * NSU;
        xrow = xsu + (size_t)rid * 64;
        yt = y1t + (size_t)b * 64 * MP_SU; MPl = MP_SU;
    } else {
        int r2 = rid - ROWS_SU;
        int b = r2 / NSV; m = r2 - b * NSV;
        xrow = xsv + (size_t)r2 * 64;
        yt = y1t + (size_t)2 * 64 * MP_SU + (size_t)b * 64 * MP_SV; MPl = MP_SV;
    }

    float xr[64];
    #pragma unroll
    for (int f4 = 0; f4 < 16; ++f4) {
        float4 v = ((const float4*)xrow)[f4];
        xr[f4 * 4 + 0] = v.x; xr[f4 * 4 + 1] = v.y;
        xr[f4 * 4 + 2] = v.z; xr[f4 * 4 + 3] = v.w;
    }
    for (int c = 0; c < 64; ++c) {
        float acc = 0.f;
        #pragma unroll
        for (int f = 0; f < 64; ++f) acc += xr[f] * sWc1[f * 64 + c];
        yt[(size_t)c * MPl + m] = f2bf(acc);
    }
    float* ini = initb + (size_t)rid * 32;
    for (int c = 0; c < 32; ++c) {
        float acc = sb[c];
        #pragma unroll
        for (int f = 0; f < 64; ++f) acc += xr[f] * sWfc1[f * 32 + c];
        ini[c] = acc;
    }
}

// ---------------- conv1 partial: p1[half][tile][16][64] = adj[:, khalf] @ y1[khalf, :] ----
// block = 4 waves = 4 independent 16-row x 64-col tiles; no LDS, no barriers;
// k64 register ping-pong prefetch for memory-level parallelism.
__global__ __launch_bounds__(256) void conv1p_kernel(
    const float* __restrict__ adj_su, const float* __restrict__ adj_sv,
    const unsigned short* __restrict__ y1t,
    float* __restrict__ p1)
{
    const int bid = blockIdx.x;
    const int half = blockIdx.y;
    int M, MP, row0, tile0, KH;
    const float* A; const unsigned short* Yt;
    if (bid < 2 * NB64_SV) {
        int b = bid / NB64_SV, rb = bid - b * NB64_SV;
        M = NSV; MP = MP_SV; KH = KH_SV;
        A  = adj_sv + (size_t)b * NSV * NSV;
        Yt = y1t + (size_t)2 * 64 * MP_SU + (size_t)b * 64 * MP_SV;
        row0 = rb * 64; tile0 = b * T_SV + rb * 4;
    } else {
        int t = bid - 2 * NB64_SV;
        int b = t / NB64_SU, rb = t - b * NB64_SU;
        M = NSU; MP = MP_SU; KH = KH_SU;
        A  = adj_su + (size_t)b * NSU * NSU;
        Yt = y1t + (size_t)b * 64 * MP_SU;
        row0 = rb * 64; tile0 = 2 * T_SV + b * T_SU + rb * 4;
    }
    const int kbeg = half ? KH : 0;
    const int kend = half ? M  : KH;

    const int tid = threadIdx.x, lane = tid & 63, wid = tid >> 6;
    const int l15 = lane & 15, kq = lane >> 4;
    const int gr  = row0 + wid * 16 + l15;
    const int grc = (gr < M) ? gr : (M - 1);
    const float* Ap  = A + (size_t)grc * M;
    const float* Apk = Ap + kq * 8;
    const unsigned short* Bp = Yt + (size_t)l15 * MP + kq * 8;
    const size_t MPg = (size_t)16 * MP;

    f32x4 acc0 = {0.f,0.f,0.f,0.f}, acc1 = acc0, acc2 = acc0, acc3 = acc0;

    float4 a0,a1,a2,a3, c0,c1,c2,c3;
    bf16x8 b0,b1,b2,b3,b4,b5,b6,b7, d0,d1,d2,d3,d4,d5,d6,d7;

#define LDA(A0,A1,A2,A3,kc) do { \
    A0 = *(const float4*)(Apk + (kc)); \
    A1 = *(const float4*)(Apk + (kc) + 4); \
    A2 = *(const float4*)(Apk + (kc) + 32); \
    A3 = *(const float4*)(Apk + (kc) + 36); } while (0)
#define LDB(B0,B1,B2,B3,B4,B5,B6,B7,kc) do { \
    B0 = *(const bf16x8*)(Bp + (kc)); \
    B1 = *(const bf16x8*)(Bp + (kc) + 32); \
    B2 = *(const bf16x8*)(Bp + MPg + (kc)); \
    B3 = *(const bf16x8*)(Bp + MPg + (kc) + 32); \
    B4 = *(const bf16x8*)(Bp + 2 * MPg + (kc)); \
    B5 = *(const bf16x8*)(Bp + 2 * MPg + (kc) + 32); \
    B6 = *(const bf16x8*)(Bp + 3 * MPg + (kc)); \
    B7 = *(const bf16x8*)(Bp + 3 * MPg + (kc) + 32); } while (0)
#define CVT(F0,F1,A0,A1,A2,A3) do { \
    F0.u[0] = pkbf(A0.x, A0.y); F0.u[1] = pkbf(A0.z, A0.w); \
    F0.u[2] = pkbf(A1.x, A1.y); F0.u[3] = pkbf(A1.z, A1.w); \
    F1.u[0] = pkbf(A2.x, A2.y); F1.u[1] = pkbf(A2.z, A2.w); \
    F1.u[2] = pkbf(A3.x, A3.y); F1.u[3] = pkbf(A3.z, A3.w); } while (0)
#define CMP8(F0,F1,B0,B1,B2,B3,B4,B5,B6,B7) do { \
    acc0 = MFMA16(F0.v, B0, acc0, 0, 0, 0); \
    acc1 = MFMA16(F0.v, B2, acc1, 0, 0, 0); \
    acc2 = MFMA16(F0.v, B4, acc2, 0, 0, 0); \
    acc3 = MFMA16(F0.v, B6, acc3, 0, 0, 0); \
    acc0 = MFMA16(F1.v, B1, acc0, 0, 0, 0); \
    acc1 = MFMA16(F1.v, B3, acc1, 0, 0, 0); \
    acc2 = MFMA16(F1.v, B5, acc2, 0, 0, 0); \
    acc3 = MFMA16(F1.v, B7, acc3, 0, 0, 0); } while (0)

    const int klast = kbeg + ((kend - kbeg) & ~63);
    if (klast > kbeg) {
        LDA(a0,a1,a2,a3, kbeg);
        LDB(b0,b1,b2,b3,b4,b5,b6,b7, kbeg);
        int kc = kbeg;
        while (kc + 128 <= klast) {
            LDA(c0,c1,c2,c3, kc + 64);
            LDB(d0,d1,d2,d3,d4,d5,d6,d7, kc + 64);
            { BF8 f0, f1; CVT(f0,f1,a0,a1,a2,a3); CMP8(f0,f1,b0,b1,b2,b3,b4,b5,b6,b7); }
            if (kc + 128 < klast) {
                LDA(a0,a1,a2,a3, kc + 128);
                LDB(b0,b1,b2,b3,b4,b5,b6,b7, kc + 128);
            }
            { BF8 f0, f1; CVT(f0,f1,c0,c1,c2,c3); CMP8(f0,f1,d0,d1,d2,d3,d4,d5,d6,d7); }
            kc += 128;
        }
        if (kc < klast) {
            BF8 f0, f1; CVT(f0,f1,a0,a1,a2,a3);
            CMP8(f0,f1,b0,b1,b2,b3,b4,b5,b6,b7);
        }
    }
    if (klast < kend) {   // guarded tail (< 64 cols)
        BF8 f0, f1;
        #pragma unroll
        for (int e = 0; e < 8; e += 2) {
            const int ka = klast + kq * 8 + e;
            const float x0 = (ka      < kend) ? Ap[ka]      : 0.f;
            const float x1 = (ka + 1  < kend) ? Ap[ka + 1]  : 0.f;
            const float y0 = (ka + 32 < kend) ? Ap[ka + 32] : 0.f;
            const float y1 = (ka + 33 < kend) ? Ap[ka + 33] : 0.f;
            f0.u[e >> 1] = pkbf(x0, x1);
            f1.u[e >> 1] = pkbf(y0, y1);
        }
        LDB(b0,b1,b2,b3,b4,b5,b6,b7, klast);
        CMP8(f0,f1,b0,b1,b2,b3,b4,b5,b6,b7);
    }
#undef LDA
#undef LDB
#undef CVT
#undef CMP8

    float* Pp = p1 + ((size_t)half * TILES_TOT + tile0 + wid) * (16 * 64);
    #pragma unroll
    for (int j = 0; j < 4; ++j) {
        const int r = kq * 4 + j;
        Pp[r * 64 +      l15] = acc0[j];
        Pp[r * 64 + 16 + l15] = acc1[j];
        Pp[r * 64 + 32 + l15] = acc2[j];
        Pp[r * 64 + 48 + l15] = acc3[j];
    }
}

// ---------------- combine1: h = relu(p0+p1+bc1); y2t = (h @ Wc2)^T bf16 ----------------
__global__ __launch_bounds__(256) void combine1_kernel(
    const float* __restrict__ p1, const float* __restrict__ bc1,
    const float* __restrict__ Wc2g, unsigned short* __restrict__ y2t)
{
    __shared__ float sW[64][32];
    __shared__ float sb[64];
    const int tid = threadIdx.x;
    for (int i = tid; i < 2048; i += 256) sW[i >> 5][i & 31] = Wc2g[i];
    if (tid < 64) sb[tid] = bc1[tid];
    __syncthreads();

    const int pr = blockIdx.x * 64 + (tid & 63);
    const int cq = tid >> 6;
    int m, M, MP; unsigned short* Yo;
    if (pr < 2 * T_SV * 16) {
        int b = pr / (T_SV * 16);
        m = pr - b * (T_SV * 16);
        M = NSV; MP = MP_SV;
        Yo = y2t + (size_t)2 * 32 * MP_SU + (size_t)b * 32 * MP_SV;
    } else {
        int t = pr - 2 * T_SV * 16;
        int b = t / (T_SU * 16);
        m = t - b * (T_SU * 16);
        M = NSU; MP = MP_SU;
        Yo = y2t + (size_t)b * 32 * MP_SU;
    }
    const float* P0 = p1 + (size_t)pr * 64;
    const float* P1 = P0 + (size_t)PADROWS * 64;
    float h[64];
    #pragma unroll
    for (int f4 = 0; f4 < 16; ++f4) {
        float4 u = ((const float4*)P0)[f4];
        float4 v = ((const float4*)P1)[f4];
        h[f4 * 4 + 0] = fmaxf(u.x + v.x + sb[f4 * 4 + 0], 0.f);
        h[f4 * 4 + 1] = fmaxf(u.y + v.y + sb[f4 * 4 + 1], 0.f);
        h[f4 * 4 + 2] = fmaxf(u.z + v.z + sb[f4 * 4 + 2], 0.f);
        h[f4 * 4 + 3] = fmaxf(u.w + v.w + sb[f4 * 4 + 3], 0.f);
    }
    float acc[8] = {0.f,0.f,0.f,0.f,0.f,0.f,0.f,0.f};
    #pragma unroll
    for (int f = 0; f < 64; ++f) {
        const float hv = h[f];
        const float4 w0 = *(const float4*)&sW[f][cq * 8];
        const float4 w1 = *(const float4*)&sW[f][cq * 8 + 4];
        acc[0] += hv * w0.x; acc[1] += hv * w0.y; acc[2] += hv * w0.z; acc[3] += hv * w0.w;
        acc[4] += hv * w1.x; acc[5] += hv * w1.y; acc[6] += hv * w1.z; acc[7] += hv * w1.w;
    }
    if (m < M) {
        #pragma unroll
        for (int j = 0; j < 8; ++j)
            Yo[(size_t)(cq * 8 + j) * MP + m] = f2bf(acc[j]);
    }
}

// ---------------- conv2 partial: p2[half][tile][16][32] = adj[:, khalf] @ y2[khalf, :] ----
__global__ __launch_bounds__(256) void conv2p_kernel(
    const float* __restrict__ adj_su, const float* __restrict__ adj_sv,
    const unsigned short* __restrict__ y2t,
    float* __restrict__ p2)
{
    const int bid = blockIdx.x;
    const int half = blockIdx.y;
    int M, MP, row0, tile0, KH;
    const float* A; const unsigned short* Yt;
    if (bid < 2 * NB64_SV) {
        int b = bid / NB64_SV, rb = bid - b * NB64_SV;
        M = NSV; MP = MP_SV; KH = KH_SV;
        A  = adj_sv + (size_t)b * NSV * NSV;
        Yt = y2t + (size_t)2 * 32 * MP_SU + (size_t)b * 32 * MP_SV;
        row0 = rb * 64; tile0 = b * T_SV + rb * 4;
    } else {
        int t = bid - 2 * NB64_SV;
        int b = t / NB64_SU, rb = t - b * NB64_SU;
        M = NSU; MP = MP_SU; KH = KH_SU;
        A  = adj_su + (size_t)b * NSU * NSU;
        Yt = y2t + (size_t)b * 32 * MP_SU;
        row0 = rb * 64; tile0 = 2 * T_SV + b * T_SU + rb * 4;
    }
    const int kbeg = half ? KH : 0;
    const int kend = half ? M  : KH;

    const int tid = threadIdx.x, lane = tid & 63, wid = tid >> 6;
    const int l15 = lane & 15, kq = lane >> 4;
    const int gr  = row0 + wid * 16 + l15;
    const int grc = (gr < M) ? gr : (M - 1);
    const float* Ap  = A + (size_t)grc * M;
    const float* Apk = Ap + kq * 8;
    const unsigned short* Bp = Yt + (size_t)l15 * MP + kq * 8;
    const size_t MPg = (size_t)16 * MP;

    f32x4 acc0 = {0.f,0.f,0.f,0.f}, acc1 = acc0;

    float4 a0,a1,a2,a3, c0,c1,c2,c3;
    bf16x8 b0,b1,b2,b3, d0,d1,d2,d3;

#define LDA(A0,A1,A2,A3,kc) do { \
    A0 = *(const float4*)(Apk + (kc)); \
    A1 = *(const float4*)(Apk + (kc) + 4); \
    A2 = *(const float4*)(Apk + (kc) + 32); \
    A3 = *(const float4*)(Apk + (kc) + 36); } while (0)
#define LDB2(B0,B1,B2,B3,kc) do { \
    B0 = *(const bf16x8*)(Bp + (kc)); \
    B1 = *(const bf16x8*)(Bp + (kc) + 32); \
    B2 = *(const bf16x8*)(Bp + MPg + (kc)); \
    B3 = *(const bf16x8*)(Bp + MPg + (kc) + 32); } while (0)
#define CVT(F0,F1,A0,A1,A2,A3) do { \
    F0.u[0] = pkbf(A0.x, A0.y); F0.u[1] = pkbf(A0.z, A0.w); \
    F0.u[2] = pkbf(A1.x, A1.y); F0.u[3] = pkbf(A1.z, A1.w); \
    F1.u[0] = pkbf(A2.x, A2.y); F1.u[1] = pkbf(A2.z, A2.w); \
    F1.u[2] = pkbf(A3.x, A3.y); F1.u[3] = pkbf(A3.z, A3.w); } while (0)
#define CMP4(F0,F1,B0,B1,B2,B3) do { \
    acc0 = MFMA16(F0.v, B0, acc0, 0, 0, 0); \
    acc1 = MFMA16(F0.v, B2, acc1, 0, 0, 0); \
    acc0 = MFMA16(F1.v, B1, acc0, 0, 0, 0); \
    acc1 = MFMA16(F1.v, B3, acc1, 0, 0, 0); } while (0)

    const int klast = kbeg + ((kend - kbeg) & ~63);
    if (klast > kbeg) {
        LDA(a0,a1,a2,a3, kbeg);
        LDB2(b0,b1,b2,b3, kbeg);
        int kc = kbeg;
        while (kc + 128 <= klast) {
            LDA(c0,c1,c2,c3, kc + 64);
            LDB2(d0,d1,d2,d3, kc + 64);
            { BF8 f0, f1; CVT(f0,f1,a0,a1,a2,a3); CMP4(f0,f1,b0,b1,b2,b3); }
            if (kc + 128 < klast) {
                LDA(a0,a1,a2,a3, kc + 128);
                LDB2(b0,b1,b2,b3, kc + 128);
            }
            { BF8 f0, f1; CVT(f0,f1,c0,c1,c2,c3); CMP4(f0,f1,d0,d1,d2,d3); }
            kc += 128;
        }
        if (kc < klast) {
            BF8 f0, f1; CVT(f0,f1,a0,a1,a2,a3);
            CMP4(f0,f1,b0,b1,b2,b3);
        }
    }
    if (klast < kend) {
        BF8 f0, f1;
        #pragma unroll
        for (int e = 0; e < 8; e += 2) {
            const int ka = klast + kq * 8 + e;
            const float x0 = (ka      < kend) ? Ap[ka]      : 0.f;
            const float x1 = (ka + 1  < kend) ? Ap[ka + 1]  : 0.f;
            const float y0 = (ka + 32 < kend) ? Ap[ka + 32] : 0.f;
            const float y1 = (ka + 33 < kend) ? Ap[ka + 33] : 0.f;
            f0.u[e >> 1] = pkbf(x0, x1);
            f1.u[e >> 1] = pkbf(y0, y1);
        }
        LDB2(b0,b1,b2,b3, klast);
        CMP4(f0,f1,b0,b1,b2,b3);
    }
#undef LDA
#undef LDB2
#undef CVT
#undef CMP4

    float* Pp = p2 + ((size_t)half * TILES_TOT + tile0 + wid) * (16 * 32);
    #pragma unroll
    for (int j = 0; j < 4; ++j) {
        const int r = kq * 4 + j;
        Pp[r * 32 +      l15] = acc0[j];
        Pp[r * 32 + 16 + l15] = acc1[j];
    }
}

// ---------------- combine2: part[tile][c] = max_r (p0+p1+bc2+init) ----------------
__global__ __launch_bounds__(256) void combine2_kernel(
    const float* __restrict__ p2, const float* __restrict__ bc2,
    const float* __restrict__ initb, float* __restrict__ part)
{
    const int idx = blockIdx.x * 256 + threadIdx.x;
    if (idx >= TILES_TOT * 32) return;
    const int gt = idx >> 5, c = idx & 31;
    int m0, M; const float* I;
    if (gt < 2 * T_SV) {
        int b = gt / T_SV;
        m0 = (gt - b * T_SV) * 16;
        M = NSV;
        I = initb + (size_t)ROWS_SU * 32 + (size_t)b * NSV * 32;
    } else {
        int t = gt - 2 * T_SV;
        int b = t / T_SU;
        m0 = (t - b * T_SU) * 16;
        M = NSU;
        I = initb + (size_t)b * NSU * 32;
    }
    const float* Q0 = p2 + (size_t)gt * 16 * 32 + c;
    const float* Q1 = Q0 + (size_t)TILES_TOT * 16 * 32;
    const float bb = bc2[c];
    float mx = NEG_INF;
    #pragma unroll
    for (int r = 0; r < 16; ++r) {
        const int m = m0 + r;
        if (m < M) {
            float v = Q0[r * 32] + Q1[r * 32] + bb + I[(size_t)m * 32 + c];
            mx = fmaxf(mx, v);
        }
    }
    part[(size_t)gt * 32 + c] = mx;
}

// ---------------- head: pool-reduce + 4-layer MLP ----------------
__global__ __launch_bounds__(128) void head_kernel(
    const float* __restrict__ part,
    const float* __restrict__ Wfc2, const float* __restrict__ bfc2,
    const float* __restrict__ Wfc3, const float* __restrict__ bfc3,
    const float* __restrict__ Wfc4, const float* __restrict__ bfc4,
    const float* __restrict__ Wfc5, const float* __restrict__ bfc5,
    float* __restrict__ out)
{
    __shared__ float d[2][64];
    __shared__ float t1[2][32];
    __shared__ float t2[2][64];
    __shared__ float t3[2][32];
    const int tid = threadIdx.x;

    if (tid < 64) {
        const int b = tid >> 5, c = tid & 31;
        float m = NEG_INF;
        const float* ps = part + (size_t)(2 * T_SV + b * T_SU) * 32 + c;
        for (int i = 0; i < T_SU; ++i) m = fmaxf(m, ps[(size_t)i * 32]);
        d[b][c] = m;
        float m2 = NEG_INF;
        const float* pv = part + (size_t)b * T_SV * 32 + c;
        for (int i = 0; i < T_SV; ++i) m2 = fmaxf(m2, pv[(size_t)i * 32]);
        d[b][32 + c] = m2;
    }
    __syncthreads();
    if (tid < 64) {
        const int b = tid >> 5, c = tid & 31;
        float acc = bfc2[c];
        for (int f = 0; f < 64; ++f) acc += d[b][f] * Wfc2[f * 32 + c];
        t1[b][c] = fmaxf(acc, 0.f);
    }
    __syncthreads();
    {
        const int b = tid >> 6, c = tid & 63;
        float acc = bfc3[c];
        for (int f = 0; f < 32; ++f) acc += t1[b][f] * Wfc3[f * 64 + c];
        t2[b][c] = fmaxf(acc, 0.f);
    }
    __syncthreads();
    if (tid < 64) {
        const int b = tid >> 5, c = tid & 31;
        float acc = bfc4[c];
        for (int f = 0; f < 64; ++f) acc += t2[b][f] * Wfc4[f * 32 + c];
        t3[b][c] = fmaxf(acc, 0.f);
    }
    __syncthreads();
    if (tid < 2) {
        float acc = bfc5[0];
        for (int f = 0; f < 32; ++f) acc += t3[tid][f] * Wfc5[f];
        out[tid] = acc;
    }
}

extern "C" void kernel_launch(void* const* d_in, const int* in_sizes, int n_in,
                              void* d_out, int out_size, void* d_ws, size_t ws_size,
                              hipStream_t stream)
{
    const float* solute_adj   = (const float*)d_in[0];
    const float* solute_meth  = (const float*)d_in[1];
    const float* solvent_meth = (const float*)d_in[2];
    const float* solvent_adj  = (const float*)d_in[3];
    const float* W_fc1 = (const float*)d_in[4];
    const float* b_fc1 = (const float*)d_in[5];
    const float* W_c1  = (const float*)d_in[6];
    const float* b_c1  = (const float*)d_in[7];
    const float* W_c2  = (const float*)d_in[8];
    const float* b_c2  = (const float*)d_in[9];
    const float* W_fc2 = (const float*)d_in[10];
    const float* b_fc2 = (const float*)d_in[11];
    const float* W_fc3 = (const float*)d_in[12];
    const float* b_fc3 = (const float*)d_in[13];
    const float* W_fc4 = (const float*)d_in[14];
    const float* b_fc4 = (const float*)d_in[15];
    const float* W_fc5 = (const float*)d_in[16];
    const float* b_fc5 = (const float*)d_in[17];
    float* out = (float*)d_out;

    // workspace layout (bytes)
    char* wsb = (char*)d_ws;
    size_t off = 0;
    unsigned short* y1t = (unsigned short*)(wsb + off); off += 2850816;       // 1425408 bf16
    unsigned short* y2t = (unsigned short*)(wsb + off); off += 1425408;       //  712704 bf16
    float* initb        = (float*)(wsb + off);          off += 2820096;       //  705024 f32
    float* p1           = (float*)(wsb + off);          off += (size_t)2 * PADROWS * 64 * 4;  // 11.3 MB
    float* p2           = p1;  // reused after combine1 (stream-ordered)
    float* part         = (float*)(wsb + off);          off += (size_t)TILES_TOT * 32 * 4;

    pre_kernel<<<dim3((ROWS_ALL + 255) / 256), dim3(256), 0, stream>>>(
        solute_meth, solvent_meth, W_c1, W_fc1, b_fc1, y1t, initb);

    dim3 gconv(2 * NB64_SV + 2 * NB64_SU, 2);   // (346, 2)
    conv1p_kernel<<<gconv, dim3(256), 0, stream>>>(solute_adj, solvent_adj, y1t, p1);

    combine1_kernel<<<dim3(PADROWS / 64), dim3(256), 0, stream>>>(p1, b_c1, W_c2, y2t);

    conv2p_kernel<<<gconv, dim3(256), 0, stream>>>(solute_adj, solvent_adj, y2t, p2);

    combine2_kernel<<<dim3((TILES_TOT * 32 + 255) / 256), dim3(256), 0, stream>>>(
        p2, b_c2, initb, part);

    head_kernel<<<dim3(1), dim3(128), 0, stream>>>(
        part, W_fc2, b_fc2, W_fc3, b_fc3, W_fc4, b_fc4, W_fc5, b_fc5, out);
}